// Round 8
// baseline (246.463 us; speedup 1.0000x reference)
//
#include <hip/hip_runtime.h>

// Gather + ragged segment XOR reduction.
// History:
//  R1/R2: direct gather 142 us — L2-miss line-fill bound (table >> 4 MB/XCD L2).
//  R4: slice-bucket + XCD-pinned gather; gather ~60 us, bucket 67 us (occupancy).
//  R5: global-atomic bucketizer regressed (139 MB scattered writes). Reverted.
//  R6: LDS-staged ordered scatter + binary-search labels: bucket ~30, gather 61.
//  R7: padded 32B rows: gather FLAT at 63 us while loads/token 5->2 and FETCH
//    28->75 MB  => gather is bound by L2 random line-request rate (~1 line per
//    token, ~8.7 req/cyc/XCD). Pad reverted.
//  R8: bucket atomics made wave-cooperative: ballot histogram (8.4M->4K LDS
//    atomics) + per-wave leader rank claims (8.4M->2.1M). Gather = R6 verbatim.

#define HPG        128     // hints per group
#define NSL        16      // slices (idx>>16), N <= 2^20
#define STAGE_CAP  12288   // tokens staged in LDS; mean 8192, +10 sigma

__device__ __forceinline__ int clip_idx(int v, int N) {
    return min(max(v, 0), N - 1);
}

// ---------------- Kernel A: bucketize (one group per block) ----------------
__global__ __launch_bounds__(1024) void bucket_kernel(
    const int* __restrict__ blocks,
    const int* __restrict__ offsets,
    const int* __restrict__ starts,
    const int* __restrict__ bs_ptr,
    const int* __restrict__ entries,     // overflow path only
    int* __restrict__ out,               // overflow path only
    unsigned int* __restrict__ buck,     // [T] u32: idx(20) | localHint(<<20)
    unsigned int* __restrict__ tab,      // [NG*NSL*2] {absBase, count}
    int H, int N, int T)
{
    __shared__ unsigned int stage[STAGE_CAP];
    __shared__ int lstart[HPG + 1];
    __shared__ unsigned int cnt[NSL], off[NSL], lcur[NSL];

    const int g    = blockIdx.x;
    const int t    = threadIdx.x;
    const int lane = t & 63;
    const int h0 = g * HPG;
    const int h1 = min(H, h0 + HPG);
    const int nh = h1 - h0;
    const int bs = bs_ptr[0];

    if (t < nh) lstart[t] = starts[h0 + t];
    if (t == 0) lstart[nh] = (h1 < H) ? starts[h1] : T;
    if (t < NSL) { cnt[t] = 0; lcur[t] = 0; }
    __syncthreads();

    const int tokBase = lstart[0];
    const int count   = lstart[nh] - tokBase;
    const int staged  = min(count, STAGE_CAP);

    // ---- pass 1: idx + hint -> LDS stage; ballot histogram (no atomics) ----
    unsigned int myCnt = 0;                  // lane k (<16) counts slice k
    for (int ib = 0; ib < staged; ib += 1024) {
        const int i = ib + t;
        unsigned int s = 16u;                // sentinel: matches no slice
        if (i < staged) {
            const int gpos = tokBase + i;
            const int idx  = clip_idx(blocks[gpos] * bs + offsets[gpos], N);
            int lo = 0, hi = nh - 1;         // largest h: lstart[h] <= gpos
            while (lo < hi) {
                int m = (lo + hi + 1) >> 1;
                if (lstart[m] <= gpos) lo = m; else hi = m - 1;
            }
            stage[i] = (unsigned int)idx | ((unsigned int)lo << 20);
            s = (unsigned int)idx >> 16;
        }
        #pragma unroll
        for (int k = 0; k < NSL; ++k) {
            unsigned long long mk = __ballot(s == (unsigned int)k);
            if (lane == k) myCnt += (unsigned int)__popcll(mk);
        }
    }
    if (lane < NSL && myCnt) atomicAdd(&cnt[lane], myCnt);
    __syncthreads();

    // exclusive prefix over 16 slice counts
    if (t == 0) {
        unsigned int run = 0;
        for (int s = 0; s < NSL; ++s) { off[s] = run; run += cnt[s]; }
    }
    __syncthreads();

    if (t < NSL) {
        tab[(g * NSL + t) * 2 + 0] = (unsigned int)tokBase + off[t];
        tab[(g * NSL + t) * 2 + 1] = cnt[t];
    }

    // ---- pass 2: ordered scatter, per-wave leader rank claims ----
    for (int ib = 0; ib < staged; ib += 1024) {
        const int i = ib + t;
        const bool act = i < staged;
        unsigned int w = 0, s = 16u;
        if (act) {
            w = stage[i];
            s = (w >> 16) & (NSL - 1);
        }
        unsigned int rank = 0;
        #pragma unroll
        for (int k = 0; k < NSL; ++k) {
            unsigned long long mk = __ballot(s == (unsigned int)k);
            if (mk) {                                  // wave-uniform
                const int leader = __ffsll((long long)mk) - 1;
                unsigned int r0 = 0;
                if (lane == leader)
                    r0 = atomicAdd(&lcur[k], (unsigned int)__popcll(mk));
                r0 = (unsigned int)__shfl((int)r0, leader);
                if (s == (unsigned int)k) {
                    const unsigned long long lt =
                        (lane == 0) ? 0ull : (~0ull >> (64 - lane));
                    rank = r0 + (unsigned int)__popcll(mk & lt);
                }
            }
        }
        if (act) buck[(unsigned int)tokBase + off[s] + rank] = w;
    }

    // overflow remainder (count > STAGE_CAP): statistically never; correctness.
    for (int i = staged + t; i < count; i += 1024) {
        const int gpos = tokBase + i;
        const int idx  = clip_idx(blocks[gpos] * bs + offsets[gpos], N);
        int lo = 0, hi = nh - 1;
        while (lo < hi) {
            int m = (lo + hi + 1) >> 1;
            if (lstart[m] <= gpos) lo = m; else hi = m - 1;
        }
        const int* row = entries + (long)idx * 5;
        int* o5 = out + (long)(h0 + lo) * 5;
        atomicXor(&o5[0], row[0]); atomicXor(&o5[1], row[1]);
        atomicXor(&o5[2], row[2]); atomicXor(&o5[3], row[3]);
        atomicXor(&o5[4], row[4]);
    }
}

// ---------------- Kernel B: XCD-pinned gather + LDS accumulate ----------------
// Grid = 2048 (resident capacity) so blockIdx&7 -> XCD round-robin holds.
// Block (x,g) touches only slices {x, x+8} -> 2.62 MB entries, L2-resident.
__global__ __launch_bounds__(256) void gather_kernel(
    const unsigned int* __restrict__ buck,
    const unsigned int* __restrict__ tab,
    const int* __restrict__ entries,
    int* __restrict__ out,
    int H, int NG, int nSl, int groupsPerBlock)
{
    __shared__ int acc[HPG * 5];

    const int B = blockIdx.x;
    const int x = B & 7;
    const int g0 = B >> 3;
    const int t = threadIdx.x;
    const int gStride = gridDim.x >> 3;

    for (int k = 0; k < groupsPerBlock; ++k) {
        const int g = g0 + k * gStride;
        if (g >= NG) break;

        for (int i = t; i < HPG * 5; i += 256) acc[i] = 0;
        __syncthreads();

        for (int s = x; s < nSl; s += 8) {
            const unsigned int base = tab[(g * NSL + s) * 2 + 0];
            const unsigned int cn   = tab[(g * NSL + s) * 2 + 1];
            for (unsigned int i = t; i < cn; i += 256) {
                const unsigned int w = buck[base + i];
                const int idx = (int)(w & 0xFFFFFu);
                const int h   = (int)(w >> 20);
                const int* row = entries + (long)idx * 5;
                atomicXor(&acc[h * 5 + 0], row[0]);
                atomicXor(&acc[h * 5 + 1], row[1]);
                atomicXor(&acc[h * 5 + 2], row[2]);
                atomicXor(&acc[h * 5 + 3], row[3]);
                atomicXor(&acc[h * 5 + 4], row[4]);
            }
        }
        __syncthreads();

        const long obase = (long)g * HPG * 5;
        const long omax  = (long)H * 5;
        for (int i = t; i < HPG * 5; i += 256) {
            const long o = obase + i;
            if (o < omax) {
                const int v = acc[i];
                if (v) atomicXor(&out[o], v);
            }
        }
        __syncthreads();
    }
}

// ---------------- Fallback (R1): direct gather, wave per hint ----------------
__global__ __launch_bounds__(256) void hint_xor_wave(
    const int* __restrict__ entries,
    const int* __restrict__ blocks,
    const int* __restrict__ offsets,
    const int* __restrict__ starts,
    const int* __restrict__ sizes,
    const int* __restrict__ bs_ptr,
    int* __restrict__ out,
    int H, int N)
{
    const int gtid = blockIdx.x * blockDim.x + threadIdx.x;
    const int hint = gtid >> 6;
    const int lane = gtid & 63;
    if (hint >= H) return;

    const int start = starts[hint];
    const int size  = sizes[hint];
    const int bs    = bs_ptr[0];

    int a0 = 0, a1 = 0, a2 = 0, a3 = 0, a4 = 0;
    for (int j = lane; j < size; j += 64) {
        int idx = clip_idx(blocks[start + j] * bs + offsets[start + j], N);
        const int* row = entries + (size_t)idx * 5;
        a0 ^= row[0]; a1 ^= row[1]; a2 ^= row[2]; a3 ^= row[3]; a4 ^= row[4];
    }
    #pragma unroll
    for (int m = 1; m < 64; m <<= 1) {
        a0 ^= __shfl_xor(a0, m);
        a1 ^= __shfl_xor(a1, m);
        a2 ^= __shfl_xor(a2, m);
        a3 ^= __shfl_xor(a3, m);
        a4 ^= __shfl_xor(a4, m);
    }
    if (lane == 0) {
        int* o = out + (size_t)hint * 5;
        o[0] = a0; o[1] = a1; o[2] = a2; o[3] = a3; o[4] = a4;
    }
}

extern "C" void kernel_launch(void* const* d_in, const int* in_sizes, int n_in,
                              void* d_out, int out_size, void* d_ws, size_t ws_size,
                              hipStream_t stream) {
    const int* entries = (const int*)d_in[0];
    const int* blocks  = (const int*)d_in[1];
    const int* offsets = (const int*)d_in[2];
    const int* starts  = (const int*)d_in[3];
    const int* sizes   = (const int*)d_in[4];
    const int* bs      = (const int*)d_in[5];
    int* out = (int*)d_out;

    const int H = in_sizes[3];
    const int T = in_sizes[1];
    const int N = in_sizes[0] / 5;

    const int NG  = (H + HPG - 1) / HPG;
    const int nSl = (N + 65535) >> 16;

    // ws layout: buck [T] u32 | tab [NG*NSL*2] u32
    const size_t buckOff   = 0;
    const size_t buckBytes = (size_t)T * 4;
    const size_t tabOff    = (buckOff + buckBytes + 63) & ~(size_t)63;
    const size_t need      = tabOff + (size_t)NG * NSL * 2 * 4 + 64;

    const bool ok = (N <= (1 << 20)) && (nSl <= NSL) && (ws_size >= need) &&
                    (H <= (1 << 27));

    if (ok) {
        unsigned int* buck = (unsigned int*)((char*)d_ws + buckOff);
        unsigned int* tab  = (unsigned int*)((char*)d_ws + tabOff);

        hipMemsetAsync(d_out, 0, (size_t)out_size * sizeof(int), stream);

        hipLaunchKernelGGL(bucket_kernel, dim3(NG), dim3(1024), 0, stream,
                           blocks, offsets, starts, bs, entries, out,
                           buck, tab, H, N, T);

        int gridB = 2048;
        if (gridB > NG * 8) gridB = NG * 8;
        const int gStride = (gridB >= 8) ? (gridB >> 3) : 1;
        const int gpb = (NG + gStride - 1) / gStride;

        hipLaunchKernelGGL(gather_kernel, dim3(gridB), dim3(256), 0, stream,
                           buck, tab, entries, out, H, NG, nSl, gpb);
    } else {
        const long total_threads = (long)H * 64;
        const int block = 256;
        const int grid = (int)((total_threads + block - 1) / block);
        hipLaunchKernelGGL(hint_xor_wave, dim3(grid), dim3(block), 0, stream,
                           entries, blocks, offsets, starts, sizes, bs, out, H, N);
    }
}

// Round 9
// 238.832 us; speedup vs baseline: 1.0320x; 1.0320x over previous
//
#include <hip/hip_runtime.h>

// Gather + ragged segment XOR reduction.
// History:
//  R1/R2: direct gather 142 us — L2-miss line-fill bound (table >> 4 MB/XCD L2).
//  R4: slice-bucket + XCD-pinned gather; gather ~60 us, bucket 67 us (occupancy).
//  R5: global-atomic bucketizer regressed (139 MB scattered writes). Reverted.
//  R6: LDS-staged ordered scatter + binary-search labels: bucket ~30, gather
//    61.4, total 189 us (best).
//  R7: padded 32B rows: gather flat (63.5) while loads/token 5->2 => not
//    L1-transaction bound. Reverted.
//  R8: ballot-aggregated bucket atomics: bucket 30->96 us (VALUBusy 88% — the
//    16-slice ballot loops cost ~4x what the LDS atomics did). Reverted.
//  R9: R6 verbatim EXCEPT gather accumulation: 5x 32-bit LDS atomicXor ->
//    2x 64-bit + 1x 32-bit (isolated A/B: LDS-atomic-bound vs L2-request-bound).

#define HPG        128     // hints per group
#define NSL        16      // slices (idx>>16), N <= 2^20
#define STAGE_CAP  12288   // tokens staged in LDS; mean 8192, +10 sigma

__device__ __forceinline__ int clip_idx(int v, int N) {
    return min(max(v, 0), N - 1);
}

__device__ __forceinline__ unsigned long long pk64(int lo, int hi) {
    return (unsigned long long)(unsigned int)lo |
           ((unsigned long long)(unsigned int)hi << 32);
}

// ---------------- Kernel A: bucketize (one group per block) — R6 form ----------------
__global__ __launch_bounds__(1024) void bucket_kernel(
    const int* __restrict__ blocks,
    const int* __restrict__ offsets,
    const int* __restrict__ starts,
    const int* __restrict__ bs_ptr,
    const int* __restrict__ entries,     // overflow path only
    int* __restrict__ out,               // overflow path only
    unsigned int* __restrict__ buck,     // [T] u32: idx(20) | localHint(<<20)
    unsigned int* __restrict__ tab,      // [NG*NSL*2] {absBase, count}
    int H, int N, int T)
{
    __shared__ unsigned int stage[STAGE_CAP];
    __shared__ int lstart[HPG + 1];
    __shared__ unsigned int cnt[NSL], off[NSL], lcur[NSL];

    const int g  = blockIdx.x;
    const int t  = threadIdx.x;
    const int h0 = g * HPG;
    const int h1 = min(H, h0 + HPG);
    const int nh = h1 - h0;
    const int bs = bs_ptr[0];

    if (t < nh) lstart[t] = starts[h0 + t];
    if (t == 0) lstart[nh] = (h1 < H) ? starts[h1] : T;
    if (t < NSL) { cnt[t] = 0; lcur[t] = 0; }
    __syncthreads();

    const int tokBase = lstart[0];
    const int count   = lstart[nh] - tokBase;
    const int staged  = min(count, STAGE_CAP);

    // pass 1: idx + hint (binary search) -> LDS stage; per-slice histogram
    for (int i = t; i < staged; i += 1024) {
        const int gpos = tokBase + i;
        const int idx  = clip_idx(blocks[gpos] * bs + offsets[gpos], N);
        int lo = 0, hi = nh - 1;                 // largest h: lstart[h] <= gpos
        while (lo < hi) {
            int m = (lo + hi + 1) >> 1;
            if (lstart[m] <= gpos) lo = m; else hi = m - 1;
        }
        stage[i] = (unsigned int)idx | ((unsigned int)lo << 20);
        atomicAdd(&cnt[(unsigned int)idx >> 16], 1u);
    }
    __syncthreads();

    // exclusive prefix over 16 slice counts
    if (t == 0) {
        unsigned int run = 0;
        for (int s = 0; s < NSL; ++s) { off[s] = run; run += cnt[s]; }
    }
    __syncthreads();

    if (t < NSL) {
        tab[(g * NSL + t) * 2 + 0] = (unsigned int)tokBase + off[t];
        tab[(g * NSL + t) * 2 + 1] = cnt[t];
    }

    // pass 2: ordered scatter into the group's own CSR range
    for (int i = t; i < staged; i += 1024) {
        const unsigned int w = stage[i];
        const unsigned int s = (w >> 16) & (NSL - 1);
        const unsigned int r = atomicAdd(&lcur[s], 1u);
        buck[(unsigned int)tokBase + off[s] + r] = w;
    }

    // overflow remainder (count > STAGE_CAP): statistically never; correctness.
    for (int i = staged + t; i < count; i += 1024) {
        const int gpos = tokBase + i;
        const int idx  = clip_idx(blocks[gpos] * bs + offsets[gpos], N);
        int lo = 0, hi = nh - 1;
        while (lo < hi) {
            int m = (lo + hi + 1) >> 1;
            if (lstart[m] <= gpos) lo = m; else hi = m - 1;
        }
        const int* row = entries + (long)idx * 5;
        int* o5 = out + (long)(h0 + lo) * 5;
        atomicXor(&o5[0], row[0]); atomicXor(&o5[1], row[1]);
        atomicXor(&o5[2], row[2]); atomicXor(&o5[3], row[3]);
        atomicXor(&o5[4], row[4]);
    }
}

// ---------------- Kernel B: XCD-pinned gather + LDS accumulate ----------------
// Grid = 2048 (resident capacity) so blockIdx&7 -> XCD round-robin holds.
// Block (x,g) touches only slices {x, x+8} -> 2.62 MB entries, L2-resident.
// R9 change: accumulate via 2x u64 + 1x u32 LDS atomicXor (was 5x u32).
__global__ __launch_bounds__(256) void gather_kernel(
    const unsigned int* __restrict__ buck,
    const unsigned int* __restrict__ tab,
    const int* __restrict__ entries,
    int* __restrict__ out,
    int H, int NG, int nSl, int groupsPerBlock)
{
    __shared__ unsigned long long accA[HPG];   // cols 0,1
    __shared__ unsigned long long accB[HPG];   // cols 2,3
    __shared__ int accC[HPG];                  // col 4

    const int B = blockIdx.x;
    const int x = B & 7;
    const int g0 = B >> 3;
    const int t = threadIdx.x;
    const int gStride = gridDim.x >> 3;

    for (int k = 0; k < groupsPerBlock; ++k) {
        const int g = g0 + k * gStride;
        if (g >= NG) break;

        for (int i = t; i < HPG; i += 256) {
            accA[i] = 0ull; accB[i] = 0ull; accC[i] = 0;
        }
        __syncthreads();

        for (int s = x; s < nSl; s += 8) {
            const unsigned int base = tab[(g * NSL + s) * 2 + 0];
            const unsigned int cn   = tab[(g * NSL + s) * 2 + 1];
            for (unsigned int i = t; i < cn; i += 256) {
                const unsigned int w = buck[base + i];
                const int idx = (int)(w & 0xFFFFFu);
                const int h   = (int)(w >> 20);
                const int* row = entries + (long)idx * 5;
                atomicXor(&accA[h], pk64(row[0], row[1]));
                atomicXor(&accB[h], pk64(row[2], row[3]));
                atomicXor(&accC[h], row[4]);
            }
        }
        __syncthreads();

        const long obase = (long)g * HPG * 5;
        const long omax  = (long)H * 5;
        for (int h = t; h < HPG; h += 256) {
            const long o = obase + (long)h * 5;
            if (o < omax) {
                const unsigned long long vA = accA[h];
                const unsigned long long vB = accB[h];
                const int a0 = (int)(unsigned int)vA;
                const int a1 = (int)(unsigned int)(vA >> 32);
                const int a2 = (int)(unsigned int)vB;
                const int a3 = (int)(unsigned int)(vB >> 32);
                const int a4 = accC[h];
                if (a0)               atomicXor(&out[o + 0], a0);
                if (a1 && o + 1 < omax) atomicXor(&out[o + 1], a1);
                if (a2 && o + 2 < omax) atomicXor(&out[o + 2], a2);
                if (a3 && o + 3 < omax) atomicXor(&out[o + 3], a3);
                if (a4 && o + 4 < omax) atomicXor(&out[o + 4], a4);
            }
        }
        __syncthreads();
    }
}

// ---------------- Fallback (R1): direct gather, wave per hint ----------------
__global__ __launch_bounds__(256) void hint_xor_wave(
    const int* __restrict__ entries,
    const int* __restrict__ blocks,
    const int* __restrict__ offsets,
    const int* __restrict__ starts,
    const int* __restrict__ sizes,
    const int* __restrict__ bs_ptr,
    int* __restrict__ out,
    int H, int N)
{
    const int gtid = blockIdx.x * blockDim.x + threadIdx.x;
    const int hint = gtid >> 6;
    const int lane = gtid & 63;
    if (hint >= H) return;

    const int start = starts[hint];
    const int size  = sizes[hint];
    const int bs    = bs_ptr[0];

    int a0 = 0, a1 = 0, a2 = 0, a3 = 0, a4 = 0;
    for (int j = lane; j < size; j += 64) {
        int idx = clip_idx(blocks[start + j] * bs + offsets[start + j], N);
        const int* row = entries + (size_t)idx * 5;
        a0 ^= row[0]; a1 ^= row[1]; a2 ^= row[2]; a3 ^= row[3]; a4 ^= row[4];
    }
    #pragma unroll
    for (int m = 1; m < 64; m <<= 1) {
        a0 ^= __shfl_xor(a0, m);
        a1 ^= __shfl_xor(a1, m);
        a2 ^= __shfl_xor(a2, m);
        a3 ^= __shfl_xor(a3, m);
        a4 ^= __shfl_xor(a4, m);
    }
    if (lane == 0) {
        int* o = out + (size_t)hint * 5;
        o[0] = a0; o[1] = a1; o[2] = a2; o[3] = a3; o[4] = a4;
    }
}

extern "C" void kernel_launch(void* const* d_in, const int* in_sizes, int n_in,
                              void* d_out, int out_size, void* d_ws, size_t ws_size,
                              hipStream_t stream) {
    const int* entries = (const int*)d_in[0];
    const int* blocks  = (const int*)d_in[1];
    const int* offsets = (const int*)d_in[2];
    const int* starts  = (const int*)d_in[3];
    const int* sizes   = (const int*)d_in[4];
    const int* bs      = (const int*)d_in[5];
    int* out = (int*)d_out;

    const int H = in_sizes[3];
    const int T = in_sizes[1];
    const int N = in_sizes[0] / 5;

    const int NG  = (H + HPG - 1) / HPG;
    const int nSl = (N + 65535) >> 16;

    // ws layout: buck [T] u32 | tab [NG*NSL*2] u32
    const size_t buckOff   = 0;
    const size_t buckBytes = (size_t)T * 4;
    const size_t tabOff    = (buckOff + buckBytes + 63) & ~(size_t)63;
    const size_t need      = tabOff + (size_t)NG * NSL * 2 * 4 + 64;

    const bool ok = (N <= (1 << 20)) && (nSl <= NSL) && (ws_size >= need) &&
                    (H <= (1 << 27));

    if (ok) {
        unsigned int* buck = (unsigned int*)((char*)d_ws + buckOff);
        unsigned int* tab  = (unsigned int*)((char*)d_ws + tabOff);

        hipMemsetAsync(d_out, 0, (size_t)out_size * sizeof(int), stream);

        hipLaunchKernelGGL(bucket_kernel, dim3(NG), dim3(1024), 0, stream,
                           blocks, offsets, starts, bs, entries, out,
                           buck, tab, H, N, T);

        int gridB = 2048;
        if (gridB > NG * 8) gridB = NG * 8;
        const int gStride = (gridB >= 8) ? (gridB >> 3) : 1;
        const int gpb = (NG + gStride - 1) / gStride;

        hipLaunchKernelGGL(gather_kernel, dim3(gridB), dim3(256), 0, stream,
                           buck, tab, entries, out, H, NG, nSl, gpb);
    } else {
        const long total_threads = (long)H * 64;
        const int block = 256;
        const int grid = (int)((total_threads + block - 1) / block);
        hipLaunchKernelGGL(hint_xor_wave, dim3(grid), dim3(block), 0, stream,
                           entries, blocks, offsets, starts, sizes, bs, out, H, N);
    }
}

// Round 10
// 188.368 us; speedup vs baseline: 1.3084x; 1.2679x over previous
//
#include <hip/hip_runtime.h>

// Gather + ragged segment XOR reduction.
// History:
//  R1/R2: direct gather 142 us — L2-miss line-fill bound (table >> 4 MB/XCD L2).
//  R4: slice-bucket + XCD-pinned gather; gather ~60, bucket 67 (occupancy).
//  R5: global-atomic bucketizer regressed (139 MB scattered writes). Reverted.
//  R6: LDS-staged ordered scatter + binary-search labels: bucket ~30, gather
//    61.4, total 189 us (best).
//  R7: padded 32B rows: gather flat => not L1-transaction bound. Reverted.
//  R8: ballot-aggregated bucket atomics: 30->96 us (VALU-bound). Reverted.
//  R9: 64-bit LDS atomicXor: gather 61->110 us, WRITE 20->100 MB — u64 LDS
//    atomics compile to a memory-backed path on gfx950. NEVER use. Reverted.
//  R10: R6 verbatim + 2-way unrolled gather token loop (doubles outstanding
//    VMEM/wave): isolates MSHR/latency-bound vs L2-request-rate-bound.

#define HPG        128     // hints per group
#define NSL        16      // slices (idx>>16), N <= 2^20
#define STAGE_CAP  12288   // tokens staged in LDS; mean 8192, +10 sigma

__device__ __forceinline__ int clip_idx(int v, int N) {
    return min(max(v, 0), N - 1);
}

// ---------------- Kernel A: bucketize (one group per block) — R6 form ----------------
__global__ __launch_bounds__(1024) void bucket_kernel(
    const int* __restrict__ blocks,
    const int* __restrict__ offsets,
    const int* __restrict__ starts,
    const int* __restrict__ bs_ptr,
    const int* __restrict__ entries,     // overflow path only
    int* __restrict__ out,               // overflow path only
    unsigned int* __restrict__ buck,     // [T] u32: idx(20) | localHint(<<20)
    unsigned int* __restrict__ tab,      // [NG*NSL*2] {absBase, count}
    int H, int N, int T)
{
    __shared__ unsigned int stage[STAGE_CAP];
    __shared__ int lstart[HPG + 1];
    __shared__ unsigned int cnt[NSL], off[NSL], lcur[NSL];

    const int g  = blockIdx.x;
    const int t  = threadIdx.x;
    const int h0 = g * HPG;
    const int h1 = min(H, h0 + HPG);
    const int nh = h1 - h0;
    const int bs = bs_ptr[0];

    if (t < nh) lstart[t] = starts[h0 + t];
    if (t == 0) lstart[nh] = (h1 < H) ? starts[h1] : T;
    if (t < NSL) { cnt[t] = 0; lcur[t] = 0; }
    __syncthreads();

    const int tokBase = lstart[0];
    const int count   = lstart[nh] - tokBase;
    const int staged  = min(count, STAGE_CAP);

    // pass 1: idx + hint (binary search) -> LDS stage; per-slice histogram
    for (int i = t; i < staged; i += 1024) {
        const int gpos = tokBase + i;
        const int idx  = clip_idx(blocks[gpos] * bs + offsets[gpos], N);
        int lo = 0, hi = nh - 1;                 // largest h: lstart[h] <= gpos
        while (lo < hi) {
            int m = (lo + hi + 1) >> 1;
            if (lstart[m] <= gpos) lo = m; else hi = m - 1;
        }
        stage[i] = (unsigned int)idx | ((unsigned int)lo << 20);
        atomicAdd(&cnt[(unsigned int)idx >> 16], 1u);
    }
    __syncthreads();

    // exclusive prefix over 16 slice counts
    if (t == 0) {
        unsigned int run = 0;
        for (int s = 0; s < NSL; ++s) { off[s] = run; run += cnt[s]; }
    }
    __syncthreads();

    if (t < NSL) {
        tab[(g * NSL + t) * 2 + 0] = (unsigned int)tokBase + off[t];
        tab[(g * NSL + t) * 2 + 1] = cnt[t];
    }

    // pass 2: ordered scatter into the group's own CSR range
    for (int i = t; i < staged; i += 1024) {
        const unsigned int w = stage[i];
        const unsigned int s = (w >> 16) & (NSL - 1);
        const unsigned int r = atomicAdd(&lcur[s], 1u);
        buck[(unsigned int)tokBase + off[s] + r] = w;
    }

    // overflow remainder (count > STAGE_CAP): statistically never; correctness.
    for (int i = staged + t; i < count; i += 1024) {
        const int gpos = tokBase + i;
        const int idx  = clip_idx(blocks[gpos] * bs + offsets[gpos], N);
        int lo = 0, hi = nh - 1;
        while (lo < hi) {
            int m = (lo + hi + 1) >> 1;
            if (lstart[m] <= gpos) lo = m; else hi = m - 1;
        }
        const int* row = entries + (long)idx * 5;
        int* o5 = out + (long)(h0 + lo) * 5;
        atomicXor(&o5[0], row[0]); atomicXor(&o5[1], row[1]);
        atomicXor(&o5[2], row[2]); atomicXor(&o5[3], row[3]);
        atomicXor(&o5[4], row[4]);
    }
}

// ---------------- Kernel B: XCD-pinned gather + LDS accumulate ----------------
// Grid = 2048 (resident capacity) so blockIdx&7 -> XCD round-robin holds.
// Block (x,g) touches only slices {x, x+8} -> 2.62 MB entries, L2-resident.
// R10: token loop unrolled 2x — both rows' loads issued before the atomics.
__global__ __launch_bounds__(256) void gather_kernel(
    const unsigned int* __restrict__ buck,
    const unsigned int* __restrict__ tab,
    const int* __restrict__ entries,
    int* __restrict__ out,
    int H, int NG, int nSl, int groupsPerBlock)
{
    __shared__ int acc[HPG * 5];

    const int B = blockIdx.x;
    const int x = B & 7;
    const int g0 = B >> 3;
    const int t = threadIdx.x;
    const int gStride = gridDim.x >> 3;

    for (int k = 0; k < groupsPerBlock; ++k) {
        const int g = g0 + k * gStride;
        if (g >= NG) break;

        for (int i = t; i < HPG * 5; i += 256) acc[i] = 0;
        __syncthreads();

        for (int s = x; s < nSl; s += 8) {
            const unsigned int base = tab[(g * NSL + s) * 2 + 0];
            const unsigned int cn   = tab[(g * NSL + s) * 2 + 1];

            unsigned int i = t;
            for (; i + 256 < cn; i += 512) {
                const unsigned int w0 = buck[base + i];
                const unsigned int w1 = buck[base + i + 256];
                const int idx0 = (int)(w0 & 0xFFFFFu);
                const int idx1 = (int)(w1 & 0xFFFFFu);
                const int h0   = (int)(w0 >> 20);
                const int h1   = (int)(w1 >> 20);
                const int* r0 = entries + (long)idx0 * 5;
                const int* r1 = entries + (long)idx1 * 5;
                // issue all 10 loads before any atomic (ILP)
                const int a0 = r0[0], a1 = r0[1], a2 = r0[2], a3 = r0[3], a4 = r0[4];
                const int b0 = r1[0], b1 = r1[1], b2 = r1[2], b3 = r1[3], b4 = r1[4];
                atomicXor(&acc[h0 * 5 + 0], a0);
                atomicXor(&acc[h0 * 5 + 1], a1);
                atomicXor(&acc[h0 * 5 + 2], a2);
                atomicXor(&acc[h0 * 5 + 3], a3);
                atomicXor(&acc[h0 * 5 + 4], a4);
                atomicXor(&acc[h1 * 5 + 0], b0);
                atomicXor(&acc[h1 * 5 + 1], b1);
                atomicXor(&acc[h1 * 5 + 2], b2);
                atomicXor(&acc[h1 * 5 + 3], b3);
                atomicXor(&acc[h1 * 5 + 4], b4);
            }
            if (i < cn) {
                const unsigned int w = buck[base + i];
                const int idx = (int)(w & 0xFFFFFu);
                const int h   = (int)(w >> 20);
                const int* row = entries + (long)idx * 5;
                atomicXor(&acc[h * 5 + 0], row[0]);
                atomicXor(&acc[h * 5 + 1], row[1]);
                atomicXor(&acc[h * 5 + 2], row[2]);
                atomicXor(&acc[h * 5 + 3], row[3]);
                atomicXor(&acc[h * 5 + 4], row[4]);
            }
        }
        __syncthreads();

        const long obase = (long)g * HPG * 5;
        const long omax  = (long)H * 5;
        for (int i = t; i < HPG * 5; i += 256) {
            const long o = obase + i;
            if (o < omax) {
                const int v = acc[i];
                if (v) atomicXor(&out[o], v);
            }
        }
        __syncthreads();
    }
}

// ---------------- Fallback (R1): direct gather, wave per hint ----------------
__global__ __launch_bounds__(256) void hint_xor_wave(
    const int* __restrict__ entries,
    const int* __restrict__ blocks,
    const int* __restrict__ offsets,
    const int* __restrict__ starts,
    const int* __restrict__ sizes,
    const int* __restrict__ bs_ptr,
    int* __restrict__ out,
    int H, int N)
{
    const int gtid = blockIdx.x * blockDim.x + threadIdx.x;
    const int hint = gtid >> 6;
    const int lane = gtid & 63;
    if (hint >= H) return;

    const int start = starts[hint];
    const int size  = sizes[hint];
    const int bs    = bs_ptr[0];

    int a0 = 0, a1 = 0, a2 = 0, a3 = 0, a4 = 0;
    for (int j = lane; j < size; j += 64) {
        int idx = clip_idx(blocks[start + j] * bs + offsets[start + j], N);
        const int* row = entries + (size_t)idx * 5;
        a0 ^= row[0]; a1 ^= row[1]; a2 ^= row[2]; a3 ^= row[3]; a4 ^= row[4];
    }
    #pragma unroll
    for (int m = 1; m < 64; m <<= 1) {
        a0 ^= __shfl_xor(a0, m);
        a1 ^= __shfl_xor(a1, m);
        a2 ^= __shfl_xor(a2, m);
        a3 ^= __shfl_xor(a3, m);
        a4 ^= __shfl_xor(a4, m);
    }
    if (lane == 0) {
        int* o = out + (size_t)hint * 5;
        o[0] = a0; o[1] = a1; o[2] = a2; o[3] = a3; o[4] = a4;
    }
}

extern "C" void kernel_launch(void* const* d_in, const int* in_sizes, int n_in,
                              void* d_out, int out_size, void* d_ws, size_t ws_size,
                              hipStream_t stream) {
    const int* entries = (const int*)d_in[0];
    const int* blocks  = (const int*)d_in[1];
    const int* offsets = (const int*)d_in[2];
    const int* starts  = (const int*)d_in[3];
    const int* sizes   = (const int*)d_in[4];
    const int* bs      = (const int*)d_in[5];
    int* out = (int*)d_out;

    const int H = in_sizes[3];
    const int T = in_sizes[1];
    const int N = in_sizes[0] / 5;

    const int NG  = (H + HPG - 1) / HPG;
    const int nSl = (N + 65535) >> 16;

    // ws layout: buck [T] u32 | tab [NG*NSL*2] u32
    const size_t buckOff   = 0;
    const size_t buckBytes = (size_t)T * 4;
    const size_t tabOff    = (buckOff + buckBytes + 63) & ~(size_t)63;
    const size_t need      = tabOff + (size_t)NG * NSL * 2 * 4 + 64;

    const bool ok = (N <= (1 << 20)) && (nSl <= NSL) && (ws_size >= need) &&
                    (H <= (1 << 27));

    if (ok) {
        unsigned int* buck = (unsigned int*)((char*)d_ws + buckOff);
        unsigned int* tab  = (unsigned int*)((char*)d_ws + tabOff);

        hipMemsetAsync(d_out, 0, (size_t)out_size * sizeof(int), stream);

        hipLaunchKernelGGL(bucket_kernel, dim3(NG), dim3(1024), 0, stream,
                           blocks, offsets, starts, bs, entries, out,
                           buck, tab, H, N, T);

        int gridB = 2048;
        if (gridB > NG * 8) gridB = NG * 8;
        const int gStride = (gridB >= 8) ? (gridB >> 3) : 1;
        const int gpb = (NG + gStride - 1) / gStride;

        hipLaunchKernelGGL(gather_kernel, dim3(gridB), dim3(256), 0, stream,
                           buck, tab, entries, out, H, NG, nSl, gpb);
    } else {
        const long total_threads = (long)H * 64;
        const int block = 256;
        const int grid = (int)((total_threads + block - 1) / block);
        hipLaunchKernelGGL(hint_xor_wave, dim3(grid), dim3(block), 0, stream,
                           entries, blocks, offsets, starts, sizes, bs, out, H, N);
    }
}